// Round 5
// baseline (50.804 us; speedup 1.0000x reference)
//
#include <hip/hip_runtime.h>
#include <math.h>

#define HH 128   // hidden size
#define SS 1000  // sequence length
#define NT 1024  // threads per block (16 waves)
#define NW (NT / 64)
#define PCT 512  // precompute threads

#define C1 2.8853900817779268f  // 2*log2(e)
#define C2 1.4426950408889634f  // log2(e)

// ws layout (floats):
//   [0..128)     a0*C1, [128..256) a1*C1, [256..384) ad*C1, [384..512) v
//   [512..640)   cc*C1 (iter-0 bias), [640..768) (cc+w3b)*C1 (iter>0 base)
//   [768..896)   w30*C1, [896..1024) w31*C1, [1024] sumv*log2(e)
__global__ __launch_bounds__(PCT) void sc_precompute(
    const float* __restrict__ enc_s_w, const float* __restrict__ enc_s_b,
    const float* __restrict__ enc_d_w, const float* __restrict__ enc_d_b,
    const float* __restrict__ v, const float* __restrict__ W,
    float* __restrict__ ws) {
    __shared__ float part[7][4][HH];
    const int t = threadIdx.x;
    const int h = t & (HH - 1);
    const int q = t >> 7;            // k-quarter 0..3
    const float4* W1 = (const float4*)(W + h * (3 * HH));
    const float4* W2 = (const float4*)(W + h * (3 * HH) + HH);
    const float4* W3 = (const float4*)(W + h * (3 * HH) + 2 * HH);
    const float4* ES = (const float4*)enc_s_w;
    const float4* ED = (const float4*)enc_d_w;
    const float4* SB = (const float4*)enc_s_b;
    const float4* DB = (const float4*)enc_d_b;
    float a0 = 0.f, a1 = 0.f, ad = 0.f, cc = 0.f, w30 = 0.f, w31 = 0.f, w3b = 0.f;
    #pragma unroll
    for (int k4 = q * 8; k4 < q * 8 + 8; ++k4) {
        float4 w1 = W1[k4], w2 = W2[k4], w3 = W3[k4];
        float4 e01 = ES[2 * k4], e23 = ES[2 * k4 + 1];
        float4 d01 = ED[2 * k4], d23 = ED[2 * k4 + 1];
        float4 sb = SB[k4], db = DB[k4];
        a0 = fmaf(w1.x, e01.x, a0); a0 = fmaf(w1.y, e01.z, a0);
        a0 = fmaf(w1.z, e23.x, a0); a0 = fmaf(w1.w, e23.z, a0);
        a1 = fmaf(w1.x, e01.y, a1); a1 = fmaf(w1.y, e01.w, a1);
        a1 = fmaf(w1.z, e23.y, a1); a1 = fmaf(w1.w, e23.w, a1);
        ad = fmaf(w2.x, d01.x + d01.y, ad); ad = fmaf(w2.y, d01.z + d01.w, ad);
        ad = fmaf(w2.z, d23.x + d23.y, ad); ad = fmaf(w2.w, d23.z + d23.w, ad);
        cc = fmaf(w1.x, sb.x, cc); cc = fmaf(w1.y, sb.y, cc);
        cc = fmaf(w1.z, sb.z, cc); cc = fmaf(w1.w, sb.w, cc);
        cc = fmaf(w2.x, db.x, cc); cc = fmaf(w2.y, db.y, cc);
        cc = fmaf(w2.z, db.z, cc); cc = fmaf(w2.w, db.w, cc);
        w30 = fmaf(w3.x, e01.x, w30); w30 = fmaf(w3.y, e01.z, w30);
        w30 = fmaf(w3.z, e23.x, w30); w30 = fmaf(w3.w, e23.z, w30);
        w31 = fmaf(w3.x, e01.y, w31); w31 = fmaf(w3.y, e01.w, w31);
        w31 = fmaf(w3.z, e23.y, w31); w31 = fmaf(w3.w, e23.w, w31);
        w3b = fmaf(w3.x, sb.x, w3b); w3b = fmaf(w3.y, sb.y, w3b);
        w3b = fmaf(w3.z, sb.z, w3b); w3b = fmaf(w3.w, sb.w, w3b);
    }
    part[0][q][h] = a0;  part[1][q][h] = a1;  part[2][q][h] = ad;
    part[3][q][h] = cc;  part[4][q][h] = w30; part[5][q][h] = w31;
    part[6][q][h] = w3b;
    __syncthreads();
    if (t < HH) {
        float r[7];
        #pragma unroll
        for (int i = 0; i < 7; ++i)
            r[i] = (part[i][0][t] + part[i][1][t]) + (part[i][2][t] + part[i][3][t]);
        ws[t]           = r[0] * C1;
        ws[HH + t]      = r[1] * C1;
        ws[2 * HH + t]  = r[2] * C1;
        ws[3 * HH + t]  = v[t];
        ws[4 * HH + t]  = r[3] * C1;
        ws[5 * HH + t]  = (r[3] + r[6]) * C1;
        ws[6 * HH + t]  = r[4] * C1;
        ws[7 * HH + t]  = r[5] * C1;
    }
    if (t == 0) {
        const float4* V4 = (const float4*)v;
        float s = 0.f;
        #pragma unroll 4
        for (int k = 0; k < HH / 4; ++k) { float4 x = V4[k]; s += x.x + x.y + x.z + x.w; }
        ws[8 * HH] = s * C2;
    }
}

// DPP row_shr:N add — reduces within each 16-lane row toward lane 15. VALU-only.
template <int CTRL>
__device__ __forceinline__ float dpp_add(float x) {
    int s = __builtin_amdgcn_update_dpp(0, __builtin_bit_cast(int, x),
                                        CTRL, 0xF, 0xF, true);
    return x + __builtin_bit_cast(float, s);
}

// 4 h-evals: acc += sum_i vv_i * sigmoid-core(z_i)   (all operands named, SROA-safe)
__device__ __forceinline__ float grp4(float4 a0, float4 a1, float4 ad, float4 vv,
                                      float4 cg, float x0, float x1, float yv,
                                      float acc) {
    float z0 = fmaf(a0.x, x0, fmaf(a1.x, x1, fmaf(ad.x, yv, cg.x)));
    float z1 = fmaf(a0.y, x0, fmaf(a1.y, x1, fmaf(ad.y, yv, cg.y)));
    float z2 = fmaf(a0.z, x0, fmaf(a1.z, x1, fmaf(ad.z, yv, cg.z)));
    float z3 = fmaf(a0.w, x0, fmaf(a1.w, x1, fmaf(ad.w, yv, cg.w)));
    float e0 = __builtin_amdgcn_exp2f(z0);
    float e1 = __builtin_amdgcn_exp2f(z1);
    float e2 = __builtin_amdgcn_exp2f(z2);
    float e3 = __builtin_amdgcn_exp2f(z3);
    acc = fmaf(vv.x, __builtin_amdgcn_rcpf(1.f + e0), acc);
    acc = fmaf(vv.y, __builtin_amdgcn_rcpf(1.f + e1), acc);
    acc = fmaf(vv.z, __builtin_amdgcn_rcpf(1.f + e2), acc);
    acc = fmaf(vv.w, __builtin_amdgcn_rcpf(1.f + e3), acc);
    return acc;
}

__device__ __forceinline__ float4 bias4(float4 cb, float4 w0, float4 w1,
                                        float X0, float X1) {
    return make_float4(fmaf(w0.x, X0, fmaf(w1.x, X1, cb.x)),
                       fmaf(w0.y, X0, fmaf(w1.y, X1, cb.y)),
                       fmaf(w0.z, X0, fmaf(w1.z, X1, cb.z)),
                       fmaf(w0.w, X0, fmaf(w1.w, X1, cb.w)));
}

__global__ __launch_bounds__(NT) void sc_main(
    const float* __restrict__ stat, const float* __restrict__ dyn,
    const float* __restrict__ ws,
    const float* __restrict__ enc_s_w, const float* __restrict__ enc_s_b,
    const float* __restrict__ dense_w, const float* __restrict__ dense_b,
    const float* __restrict__ lin_w, const float* __restrict__ lin_b,
    float* __restrict__ out) {
    const int b    = blockIdx.x;
    const int t    = threadIdx.x;
    const int wave = t >> 6;
    const int lane = t & 63;
    const int g    = t & 15;   // h-slice: h = 8g .. 8g+7
    const int sg   = t >> 4;   // s-group 0..63; s = pass*64 + sg

    __shared__ __align__(16) float4 xs[NT];
    __shared__ float4 red4[2][NW];
    __shared__ __align__(16) float hy_sh[HH];

    // stage per-s inputs to LDS (coalesced)
    {
        float x0 = 0.f, x1 = 0.f, yv = 0.f;
        if (t < SS) {
            const float* sb = stat + (size_t)b * 2 * SS;
            x0 = sb[t];
            x1 = sb[SS + t];
            yv = dyn[(size_t)b * 2 * SS + SS + t];
        }
        xs[t] = make_float4(x0, x1, yv, 0.f);
    }

    // register-resident constants: 16 named float4 (no arrays -> no scratch)
    const float* wp = ws + g * 8;
    const float4 a0L = *(const float4*)(wp);
    const float4 a0H = *(const float4*)(wp + 4);
    const float4 a1L = *(const float4*)(wp + HH);
    const float4 a1H = *(const float4*)(wp + HH + 4);
    const float4 adL = *(const float4*)(wp + 2 * HH);
    const float4 adH = *(const float4*)(wp + 2 * HH + 4);
    const float4 vvL = *(const float4*)(wp + 3 * HH);
    const float4 vvH = *(const float4*)(wp + 3 * HH + 4);
    const float4 c0L = *(const float4*)(wp + 4 * HH);
    const float4 c0H = *(const float4*)(wp + 4 * HH + 4);
    const float4 cbL = *(const float4*)(wp + 5 * HH);
    const float4 cbH = *(const float4*)(wp + 5 * HH + 4);
    const float4 w0L = *(const float4*)(wp + 6 * HH);
    const float4 w0H = *(const float4*)(wp + 6 * HH + 4);
    const float4 w1L = *(const float4*)(wp + 7 * HH);
    const float4 w1H = *(const float4*)(wp + 7 * HH + 4);
    const float svc2 = ws[8 * HH];

    __syncthreads();  // xs ready

    float X0 = 0.f, X1 = 0.f;

    auto run_iter = [&](float4 cgL, float4 cgH, int parity) {
        float S = 0.f, Sx0 = 0.f, Sx1 = 0.f;
        for (int pass = 0; pass < 16; ++pass) {
            const int s = pass * 64 + sg;
            float4 x = xs[s];
            float acc = grp4(a0L, a1L, adL, vvL, cgL, x.x, x.y, x.z, 0.f);
            acc = grp4(a0H, a1H, adH, vvH, cgH, x.x, x.y, x.z, acc);
            acc = dpp_add<0x118>(acc);  // row_shr:8
            acc = dpp_add<0x114>(acc);  // row_shr:4
            acc = dpp_add<0x112>(acc);  // row_shr:2
            acc = dpp_add<0x111>(acc);  // row_shr:1
            const bool own = (g == 15) && (s < SS);
            float arg = own ? fmaf(-C1, acc, svc2) : -200.f;  // exp2(-200) == +0
            float p = __builtin_amdgcn_exp2f(arg);
            S   += p;
            Sx0  = fmaf(p, x.x, Sx0);
            Sx1  = fmaf(p, x.y, Sx1);
        }
        S   += __shfl_xor(S, 16);   S   += __shfl_xor(S, 32);
        Sx0 += __shfl_xor(Sx0, 16); Sx0 += __shfl_xor(Sx0, 32);
        Sx1 += __shfl_xor(Sx1, 16); Sx1 += __shfl_xor(Sx1, 32);
        if (lane == 15) red4[parity][wave] = make_float4(S, Sx0, Sx1, 0.f);
        __syncthreads();  // only barrier per iteration
        float4 w4 = red4[parity][lane & 15];
        #pragma unroll
        for (int off = 1; off < 16; off <<= 1) {
            w4.x += __shfl_xor(w4.x, off);
            w4.y += __shfl_xor(w4.y, off);
            w4.z += __shfl_xor(w4.z, off);
        }
        float inv = __builtin_amdgcn_rcpf(w4.x);
        X0 = w4.y * inv;  // uniform across block
        X1 = w4.z * inv;
    };

    run_iter(c0L, c0H, 0);
    run_iter(bias4(cbL, w0L, w1L, X0, X1), bias4(cbH, w0H, w1H, X0, X1), 1);
    run_iter(bias4(cbL, w0L, w1L, X0, X1), bias4(cbH, w0H, w1H, X0, X1), 0);

    // hy[h] = enc_s_w[h,0]*X0 + enc_s_w[h,1]*X1 + enc_s_b[h]
    if (t < HH)
        hy_sh[t] = fmaf(enc_s_w[2 * t], X0, fmaf(enc_s_w[2 * t + 1], X1, enc_s_b[t]));
    __syncthreads();

    // out[b] = lin_w @ relu(dense_w @ hy + dense_b) + lin_b
    float o = 0.f;
    if (t < HH) {
        const float4* dw4 = (const float4*)(dense_w + t * HH);
        const float4* hy4 = (const float4*)hy_sh;
        float r = dense_b[t];
        #pragma unroll 4
        for (int k = 0; k < HH / 4; ++k) {
            float4 d4 = dw4[k], h4 = hy4[k];
            r = fmaf(d4.x, h4.x, fmaf(d4.y, h4.y, fmaf(d4.z, h4.z, fmaf(d4.w, h4.w, r))));
        }
        o = lin_w[t] * fmaxf(r, 0.f);
    }
    #pragma unroll
    for (int off = 32; off > 0; off >>= 1) o += __shfl_xor(o, off);
    if (lane == 0) red4[0][wave].x = o;
    __syncthreads();
    if (t == 0) {
        float s = 0.f;
        for (int i = 0; i < NW; ++i) s += red4[0][i].x;
        out[b] = s + lin_b[0];
    }
}

extern "C" void kernel_launch(void* const* d_in, const int* in_sizes, int n_in,
                              void* d_out, int out_size, void* d_ws, size_t ws_size,
                              hipStream_t stream) {
    const float* stat    = (const float*)d_in[0];
    const float* dyn     = (const float*)d_in[1];
    const float* enc_s_w = (const float*)d_in[2];
    const float* enc_s_b = (const float*)d_in[3];
    const float* enc_d_w = (const float*)d_in[4];
    const float* enc_d_b = (const float*)d_in[5];
    const float* v       = (const float*)d_in[6];
    const float* W       = (const float*)d_in[7];
    const float* dense_w = (const float*)d_in[8];
    const float* dense_b = (const float*)d_in[9];
    const float* lin_w   = (const float*)d_in[10];
    const float* lin_b   = (const float*)d_in[11];
    float* out = (float*)d_out;
    float* ws  = (float*)d_ws;

    const int B = in_sizes[0] / (2 * SS);

    hipLaunchKernelGGL(sc_precompute, dim3(1), dim3(PCT), 0, stream,
                       enc_s_w, enc_s_b, enc_d_w, enc_d_b, v, W, ws);
    hipLaunchKernelGGL(sc_main, dim3(B), dim3(NT), 0, stream,
                       stat, dyn, ws, enc_s_w, enc_s_b, dense_w, dense_b,
                       lin_w, lin_b, out);
}

// Round 6
// 47.960 us; speedup vs baseline: 1.0593x; 1.0593x over previous
//
#include <hip/hip_runtime.h>
#include <math.h>

#define HH 128   // hidden size
#define SS 1000  // sequence length
#define NT 1024  // threads per block (16 waves)
#define NW (NT / 64)

#define C1 2.8853900817779268f  // 2*log2(e)
#define C2 1.4426950408889634f  // log2(e)

// Opaque register pin: value must be materialized in a VGPR here and cannot
// be rematerialized/reloaded later (defeats the backend's load-remat when it
// chases a low register-pressure target).
__device__ __forceinline__ void pin(float& x) { asm volatile("" : "+v"(x)); }

// DPP row_shr:N add — reduces within each 16-lane row toward lane 15. VALU-only.
template <int CTRL>
__device__ __forceinline__ float dpp_add(float x) {
    int s = __builtin_amdgcn_update_dpp(0, __builtin_bit_cast(int, x),
                                        CTRL, 0xF, 0xF, true);
    return x + __builtin_bit_cast(float, s);
}

__global__ __launch_bounds__(NT, 4) void sc_fused(
    const float* __restrict__ stat, const float* __restrict__ dyn,
    const float* __restrict__ enc_s_w, const float* __restrict__ enc_s_b,
    const float* __restrict__ enc_d_w, const float* __restrict__ enc_d_b,
    const float* __restrict__ v, const float* __restrict__ W,
    const float* __restrict__ dense_w, const float* __restrict__ dense_b,
    const float* __restrict__ lin_w, const float* __restrict__ lin_b,
    float* __restrict__ out) {
    const int b    = blockIdx.x;
    const int t    = threadIdx.x;
    const int wave = t >> 6;
    const int lane = t & 63;
    const int g    = t & 15;   // h-slice: h = 8g .. 8g+7
    const int sg   = t >> 4;   // s-group 0..63; s = pass*64 + sg

    __shared__ float part[7][8][HH];              // split-k partials (28 KB)
    __shared__ __align__(16) float4 xs[NT];       // {x0,x1,yv,0} per s (16 KB)
    __shared__ __align__(16) float kc[8][HH];     // folded constants (4 KB)
    __shared__ float4 red4[2][NW];
    __shared__ float hy_sh[HH];
    __shared__ float svc2_sh;

    // ---- phase 0: stage per-s inputs (coalesced) ----
    {
        float x0 = 0.f, x1 = 0.f, yv = 0.f;
        if (t < SS) {
            const float* sb = stat + (size_t)b * 2 * SS;
            x0 = sb[t];
            x1 = sb[SS + t];
            yv = dyn[(size_t)b * 2 * SS + SS + t];
        }
        xs[t] = make_float4(x0, x1, yv, 0.f);
    }

    // ---- phase 1: per-block constant folding (split-k x 8) ----
    {
        const int h = t & (HH - 1);
        const int q = t >> 7;  // k-eighth 0..7
        const float4* W1 = (const float4*)(W + h * (3 * HH));
        const float4* W2 = (const float4*)(W + h * (3 * HH) + HH);
        const float4* W3 = (const float4*)(W + h * (3 * HH) + 2 * HH);
        const float4* ES = (const float4*)enc_s_w;
        const float4* ED = (const float4*)enc_d_w;
        const float4* SB = (const float4*)enc_s_b;
        const float4* DB = (const float4*)enc_d_b;
        float a0 = 0.f, a1 = 0.f, ad = 0.f, cc = 0.f, w30 = 0.f, w31 = 0.f, w3b = 0.f;
        #pragma unroll
        for (int k4 = q * 4; k4 < q * 4 + 4; ++k4) {
            float4 w1 = W1[k4], w2 = W2[k4], w3 = W3[k4];
            float4 e01 = ES[2 * k4], e23 = ES[2 * k4 + 1];
            float4 d01 = ED[2 * k4], d23 = ED[2 * k4 + 1];
            float4 sb = SB[k4], db = DB[k4];
            a0 = fmaf(w1.x, e01.x, a0); a0 = fmaf(w1.y, e01.z, a0);
            a0 = fmaf(w1.z, e23.x, a0); a0 = fmaf(w1.w, e23.z, a0);
            a1 = fmaf(w1.x, e01.y, a1); a1 = fmaf(w1.y, e01.w, a1);
            a1 = fmaf(w1.z, e23.y, a1); a1 = fmaf(w1.w, e23.w, a1);
            ad = fmaf(w2.x, d01.x + d01.y, ad); ad = fmaf(w2.y, d01.z + d01.w, ad);
            ad = fmaf(w2.z, d23.x + d23.y, ad); ad = fmaf(w2.w, d23.z + d23.w, ad);
            cc = fmaf(w1.x, sb.x, cc); cc = fmaf(w1.y, sb.y, cc);
            cc = fmaf(w1.z, sb.z, cc); cc = fmaf(w1.w, sb.w, cc);
            cc = fmaf(w2.x, db.x, cc); cc = fmaf(w2.y, db.y, cc);
            cc = fmaf(w2.z, db.z, cc); cc = fmaf(w2.w, db.w, cc);
            w30 = fmaf(w3.x, e01.x, w30); w30 = fmaf(w3.y, e01.z, w30);
            w30 = fmaf(w3.z, e23.x, w30); w30 = fmaf(w3.w, e23.z, w30);
            w31 = fmaf(w3.x, e01.y, w31); w31 = fmaf(w3.y, e01.w, w31);
            w31 = fmaf(w3.z, e23.y, w31); w31 = fmaf(w3.w, e23.w, w31);
            w3b = fmaf(w3.x, sb.x, w3b); w3b = fmaf(w3.y, sb.y, w3b);
            w3b = fmaf(w3.z, sb.z, w3b); w3b = fmaf(w3.w, sb.w, w3b);
        }
        part[0][q][h] = a0;  part[1][q][h] = a1;  part[2][q][h] = ad;
        part[3][q][h] = cc;  part[4][q][h] = w30; part[5][q][h] = w31;
        part[6][q][h] = w3b;
    }
    __syncthreads();

    // ---- phase 2: reduce partials, build kc ----
    if (t < HH) {
        float r0 = 0.f, r1 = 0.f, r2 = 0.f, r3 = 0.f, r4 = 0.f, r5 = 0.f, r6 = 0.f;
        #pragma unroll
        for (int q = 0; q < 8; ++q) {
            r0 += part[0][q][t]; r1 += part[1][q][t]; r2 += part[2][q][t];
            r3 += part[3][q][t]; r4 += part[4][q][t]; r5 += part[5][q][t];
            r6 += part[6][q][t];
        }
        kc[0][t] = r0 * C1;          // a0*C1
        kc[1][t] = r1 * C1;          // a1*C1
        kc[2][t] = r2 * C1;          // ad*C1
        kc[3][t] = v[t];             // v
        kc[4][t] = r3 * C1;          // cc*C1 (iter-0 bias)
        kc[5][t] = (r3 + r6) * C1;   // (cc+w3b)*C1
        kc[6][t] = r4 * C1;          // w30*C1
        kc[7][t] = r5 * C1;          // w31*C1
    } else if (t < 160) {            // wave 2, lanes 0..31: sum(v)
        int j = t - 128;
        float4 x = ((const float4*)v)[j];
        float s = (x.x + x.y) + (x.z + x.w);
        #pragma unroll
        for (int off = 1; off < 32; off <<= 1) s += __shfl_xor(s, off);
        if (t == 128) svc2_sh = s * C2;
    }
    __syncthreads();

    // ---- phase 3: pin the hot constants into registers ----
    const int h0 = g * 8;
    float4 f;
    f = *(const float4*)&kc[0][h0];     float a00 = f.x, a01 = f.y, a02 = f.z, a03 = f.w;
    f = *(const float4*)&kc[0][h0 + 4]; float a04 = f.x, a05 = f.y, a06 = f.z, a07 = f.w;
    f = *(const float4*)&kc[1][h0];     float a10 = f.x, a11 = f.y, a12 = f.z, a13 = f.w;
    f = *(const float4*)&kc[1][h0 + 4]; float a14 = f.x, a15 = f.y, a16 = f.z, a17 = f.w;
    f = *(const float4*)&kc[2][h0];     float ad0 = f.x, ad1 = f.y, ad2 = f.z, ad3 = f.w;
    f = *(const float4*)&kc[2][h0 + 4]; float ad4 = f.x, ad5 = f.y, ad6 = f.z, ad7 = f.w;
    f = *(const float4*)&kc[3][h0];     float vv0 = f.x, vv1 = f.y, vv2 = f.z, vv3 = f.w;
    f = *(const float4*)&kc[3][h0 + 4]; float vv4 = f.x, vv5 = f.y, vv6 = f.z, vv7 = f.w;
    pin(a00); pin(a01); pin(a02); pin(a03); pin(a04); pin(a05); pin(a06); pin(a07);
    pin(a10); pin(a11); pin(a12); pin(a13); pin(a14); pin(a15); pin(a16); pin(a17);
    pin(ad0); pin(ad1); pin(ad2); pin(ad3); pin(ad4); pin(ad5); pin(ad6); pin(ad7);
    pin(vv0); pin(vv1); pin(vv2); pin(vv3); pin(vv4); pin(vv5); pin(vv6); pin(vv7);
    float svc2 = svc2_sh;
    pin(svc2);

    float X0 = 0.f, X1 = 0.f;

    auto run_iter = [&](int iter, int parity) {
        // per-iter bias cg[h] (8 named regs, pinned)
        float cg0, cg1, cg2, cg3, cg4, cg5, cg6, cg7;
        if (iter == 0) {
            float4 lo = *(const float4*)&kc[4][h0];
            float4 hi = *(const float4*)&kc[4][h0 + 4];
            cg0 = lo.x; cg1 = lo.y; cg2 = lo.z; cg3 = lo.w;
            cg4 = hi.x; cg5 = hi.y; cg6 = hi.z; cg7 = hi.w;
        } else {
            float4 cbl = *(const float4*)&kc[5][h0];
            float4 cbh = *(const float4*)&kc[5][h0 + 4];
            float4 w0l = *(const float4*)&kc[6][h0];
            float4 w0h = *(const float4*)&kc[6][h0 + 4];
            float4 w1l = *(const float4*)&kc[7][h0];
            float4 w1h = *(const float4*)&kc[7][h0 + 4];
            cg0 = fmaf(w0l.x, X0, fmaf(w1l.x, X1, cbl.x));
            cg1 = fmaf(w0l.y, X0, fmaf(w1l.y, X1, cbl.y));
            cg2 = fmaf(w0l.z, X0, fmaf(w1l.z, X1, cbl.z));
            cg3 = fmaf(w0l.w, X0, fmaf(w1l.w, X1, cbl.w));
            cg4 = fmaf(w0h.x, X0, fmaf(w1h.x, X1, cbh.x));
            cg5 = fmaf(w0h.y, X0, fmaf(w1h.y, X1, cbh.y));
            cg6 = fmaf(w0h.z, X0, fmaf(w1h.z, X1, cbh.z));
            cg7 = fmaf(w0h.w, X0, fmaf(w1h.w, X1, cbh.w));
        }
        pin(cg0); pin(cg1); pin(cg2); pin(cg3);
        pin(cg4); pin(cg5); pin(cg6); pin(cg7);

        float S = 0.f, Sx0 = 0.f, Sx1 = 0.f;
        #pragma unroll 4
        for (int pass = 0; pass < 16; ++pass) {
            const int s = pass * 64 + sg;
            float4 x = xs[s];
            float z0 = fmaf(a00, x.x, fmaf(a10, x.y, fmaf(ad0, x.z, cg0)));
            float z1 = fmaf(a01, x.x, fmaf(a11, x.y, fmaf(ad1, x.z, cg1)));
            float z2 = fmaf(a02, x.x, fmaf(a12, x.y, fmaf(ad2, x.z, cg2)));
            float z3 = fmaf(a03, x.x, fmaf(a13, x.y, fmaf(ad3, x.z, cg3)));
            float z4 = fmaf(a04, x.x, fmaf(a14, x.y, fmaf(ad4, x.z, cg4)));
            float z5 = fmaf(a05, x.x, fmaf(a15, x.y, fmaf(ad5, x.z, cg5)));
            float z6 = fmaf(a06, x.x, fmaf(a16, x.y, fmaf(ad6, x.z, cg6)));
            float z7 = fmaf(a07, x.x, fmaf(a17, x.y, fmaf(ad7, x.z, cg7)));
            float e0 = __builtin_amdgcn_exp2f(z0);
            float e1 = __builtin_amdgcn_exp2f(z1);
            float e2 = __builtin_amdgcn_exp2f(z2);
            float e3 = __builtin_amdgcn_exp2f(z3);
            float e4 = __builtin_amdgcn_exp2f(z4);
            float e5 = __builtin_amdgcn_exp2f(z5);
            float e6 = __builtin_amdgcn_exp2f(z6);
            float e7 = __builtin_amdgcn_exp2f(z7);
            float acc;
            acc = fmaf(vv0, __builtin_amdgcn_rcpf(1.f + e0), 0.f);
            acc = fmaf(vv1, __builtin_amdgcn_rcpf(1.f + e1), acc);
            acc = fmaf(vv2, __builtin_amdgcn_rcpf(1.f + e2), acc);
            acc = fmaf(vv3, __builtin_amdgcn_rcpf(1.f + e3), acc);
            acc = fmaf(vv4, __builtin_amdgcn_rcpf(1.f + e4), acc);
            acc = fmaf(vv5, __builtin_amdgcn_rcpf(1.f + e5), acc);
            acc = fmaf(vv6, __builtin_amdgcn_rcpf(1.f + e6), acc);
            acc = fmaf(vv7, __builtin_amdgcn_rcpf(1.f + e7), acc);
            // reduce over the 16-lane h-group -> lane g==15 holds the total
            acc = dpp_add<0x118>(acc);  // row_shr:8
            acc = dpp_add<0x114>(acc);  // row_shr:4
            acc = dpp_add<0x112>(acc);  // row_shr:2
            acc = dpp_add<0x111>(acc);  // row_shr:1
            const bool own = (g == 15) && (s < SS);
            float arg = own ? fmaf(-C1, acc, svc2) : -200.f;  // exp2(-200) == +0
            float p = __builtin_amdgcn_exp2f(arg);
            S   += p;
            Sx0  = fmaf(p, x.x, Sx0);
            Sx1  = fmaf(p, x.y, Sx1);
        }
        S   += __shfl_xor(S, 16);   S   += __shfl_xor(S, 32);
        Sx0 += __shfl_xor(Sx0, 16); Sx0 += __shfl_xor(Sx0, 32);
        Sx1 += __shfl_xor(Sx1, 16); Sx1 += __shfl_xor(Sx1, 32);
        if (lane == 15) red4[parity][wave] = make_float4(S, Sx0, Sx1, 0.f);
        __syncthreads();  // only barrier per iteration
        float4 w4 = red4[parity][lane & 15];
        #pragma unroll
        for (int off = 1; off < 16; off <<= 1) {
            w4.x += __shfl_xor(w4.x, off);
            w4.y += __shfl_xor(w4.y, off);
            w4.z += __shfl_xor(w4.z, off);
        }
        float inv = __builtin_amdgcn_rcpf(w4.x);
        X0 = w4.y * inv;  // uniform across block
        X1 = w4.z * inv;
    };

    run_iter(0, 0);
    run_iter(1, 1);
    run_iter(2, 0);

    // hy[h] = enc_s_w[h,0]*X0 + enc_s_w[h,1]*X1 + enc_s_b[h]
    if (t < HH)
        hy_sh[t] = fmaf(enc_s_w[2 * t], X0, fmaf(enc_s_w[2 * t + 1], X1, enc_s_b[t]));
    __syncthreads();

    // out[b] = lin_w @ relu(dense_w @ hy + dense_b) + lin_b
    float o = 0.f;
    if (t < HH) {
        const float4* dw4 = (const float4*)(dense_w + t * HH);
        const float4* hy4 = (const float4*)hy_sh;
        float r = dense_b[t];
        #pragma unroll 4
        for (int k = 0; k < HH / 4; ++k) {
            float4 d4 = dw4[k], h4 = hy4[k];
            r = fmaf(d4.x, h4.x, fmaf(d4.y, h4.y, fmaf(d4.z, h4.z, fmaf(d4.w, h4.w, r))));
        }
        o = lin_w[t] * fmaxf(r, 0.f);
    }
    #pragma unroll
    for (int off = 32; off > 0; off >>= 1) o += __shfl_xor(o, off);
    if (lane == 0) red4[0][wave].x = o;
    __syncthreads();
    if (t == 0) {
        float s = 0.f;
        for (int i = 0; i < NW; ++i) s += red4[0][i].x;
        out[b] = s + lin_b[0];
    }
}

extern "C" void kernel_launch(void* const* d_in, const int* in_sizes, int n_in,
                              void* d_out, int out_size, void* d_ws, size_t ws_size,
                              hipStream_t stream) {
    const float* stat    = (const float*)d_in[0];
    const float* dyn     = (const float*)d_in[1];
    const float* enc_s_w = (const float*)d_in[2];
    const float* enc_s_b = (const float*)d_in[3];
    const float* enc_d_w = (const float*)d_in[4];
    const float* enc_d_b = (const float*)d_in[5];
    const float* v       = (const float*)d_in[6];
    const float* W       = (const float*)d_in[7];
    const float* dense_w = (const float*)d_in[8];
    const float* dense_b = (const float*)d_in[9];
    const float* lin_w   = (const float*)d_in[10];
    const float* lin_b   = (const float*)d_in[11];
    float* out = (float*)d_out;

    const int B = in_sizes[0] / (2 * SS);

    hipLaunchKernelGGL(sc_fused, dim3(B), dim3(NT), 0, stream,
                       stat, dyn, enc_s_w, enc_s_b, enc_d_w, enc_d_b, v, W,
                       dense_w, dense_b, lin_w, lin_b, out);
}

// Round 7
// 43.007 us; speedup vs baseline: 1.1813x; 1.1152x over previous
//
#include <hip/hip_runtime.h>
#include <math.h>

#define HH 128   // hidden size
#define SS 1000  // sequence length
#define NT 1024  // threads per block (16 waves)
#define NW (NT / 64)

#define C1 2.8853900817779268f  // 2*log2(e)
#define C2 1.4426950408889634f  // log2(e)

typedef float v2f __attribute__((ext_vector_type(2)));

__device__ __forceinline__ void pinf(float& x) { asm volatile("" : "+v"(x)); }
__device__ __forceinline__ void pin2(v2f& x)   { asm volatile("" : "+v"(x)); }

// DPP row_shr:N add — suffix-reduce within 8-lane groups toward lane 7 of each group.
template <int CTRL>
__device__ __forceinline__ float dpp_add(float x) {
    int s = __builtin_amdgcn_update_dpp(0, __builtin_bit_cast(int, x),
                                        CTRL, 0xF, 0xF, true);
    return x + __builtin_bit_cast(float, s);
}

#define LD16(P, ROW)                                                         \
    {                                                                        \
        const float4* p4_ = (const float4*)&kc[ROW][h0];                     \
        float4 u0_ = p4_[0], u1_ = p4_[1], u2_ = p4_[2], u3_ = p4_[3];       \
        P##0 = (v2f){u0_.x, u0_.y}; P##1 = (v2f){u0_.z, u0_.w};              \
        P##2 = (v2f){u1_.x, u1_.y}; P##3 = (v2f){u1_.z, u1_.w};              \
        P##4 = (v2f){u2_.x, u2_.y}; P##5 = (v2f){u2_.z, u2_.w};              \
        P##6 = (v2f){u3_.x, u3_.y}; P##7 = (v2f){u3_.z, u3_.w};              \
    }

#define PIN8(P) { pin2(P##0); pin2(P##1); pin2(P##2); pin2(P##3);            \
                  pin2(P##4); pin2(P##5); pin2(P##6); pin2(P##7); }

// one h-pair: z = a0*x0 + a1*x1 + ad*yv + cg (pk_fma x3); e = exp2(z);
// acc2 += vv * rcp(1 + e)  (pk_add + 2 rcp + pk_fma)
#define HPAIR(J)                                                             \
    {                                                                        \
        v2f z_ = __builtin_elementwise_fma(                                  \
            a0_##J, vx0,                                                     \
            __builtin_elementwise_fma(                                       \
                a1_##J, vx1,                                                 \
                __builtin_elementwise_fma(ad_##J, vyv, cg_##J)));            \
        v2f e_;                                                              \
        e_.x = __builtin_amdgcn_exp2f(z_.x);                                 \
        e_.y = __builtin_amdgcn_exp2f(z_.y);                                 \
        v2f d_ = e_ + one2;                                                  \
        v2f r_;                                                              \
        r_.x = __builtin_amdgcn_rcpf(d_.x);                                  \
        r_.y = __builtin_amdgcn_rcpf(d_.y);                                  \
        acc2 = __builtin_elementwise_fma(vv_##J, r_, acc2);                  \
    }

__global__ __launch_bounds__(NT, 4) void sc_fused(
    const float* __restrict__ stat, const float* __restrict__ dyn,
    const float* __restrict__ enc_s_w, const float* __restrict__ enc_s_b,
    const float* __restrict__ enc_d_w, const float* __restrict__ enc_d_b,
    const float* __restrict__ v, const float* __restrict__ W,
    const float* __restrict__ dense_w, const float* __restrict__ dense_b,
    const float* __restrict__ lin_w, const float* __restrict__ lin_b,
    float* __restrict__ out) {
    const int b    = blockIdx.x;
    const int t    = threadIdx.x;
    const int wave = t >> 6;
    const int lane = t & 63;
    const int g8   = t & 7;    // position within 8-lane h-group; h = g8*16 .. +15
    const int sg   = t >> 3;   // s-group 0..127; s = pass*128 + sg

    __shared__ float part[7][8][HH];              // split-k partials (28 KB)
    __shared__ __align__(16) float4 xs[NT];       // {x0,x1,yv,0} per s (16 KB)
    __shared__ __align__(16) float kc[8][HH];     // folded constants (4 KB)
    __shared__ float4 red4[2][NW];
    __shared__ float hy_sh[HH];
    __shared__ float svc2_sh;

    // ---- phase 0: stage per-s inputs (coalesced) ----
    {
        float x0 = 0.f, x1 = 0.f, yv = 0.f;
        if (t < SS) {
            const float* sb = stat + (size_t)b * 2 * SS;
            x0 = sb[t];
            x1 = sb[SS + t];
            yv = dyn[(size_t)b * 2 * SS + SS + t];
        }
        xs[t] = make_float4(x0, x1, yv, 0.f);
    }

    // ---- phase 1: per-block constant folding (split-k x 8) ----
    {
        const int h = t & (HH - 1);
        const int q = t >> 7;  // k-eighth 0..7
        const float4* W1 = (const float4*)(W + h * (3 * HH));
        const float4* W2 = (const float4*)(W + h * (3 * HH) + HH);
        const float4* W3 = (const float4*)(W + h * (3 * HH) + 2 * HH);
        const float4* ES = (const float4*)enc_s_w;
        const float4* ED = (const float4*)enc_d_w;
        const float4* SB = (const float4*)enc_s_b;
        const float4* DB = (const float4*)enc_d_b;
        float a0 = 0.f, a1 = 0.f, ad = 0.f, cc = 0.f, w30 = 0.f, w31 = 0.f, w3b = 0.f;
        #pragma unroll
        for (int k4 = q * 4; k4 < q * 4 + 4; ++k4) {
            float4 w1 = W1[k4], w2 = W2[k4], w3 = W3[k4];
            float4 e01 = ES[2 * k4], e23 = ES[2 * k4 + 1];
            float4 d01 = ED[2 * k4], d23 = ED[2 * k4 + 1];
            float4 sb = SB[k4], db = DB[k4];
            a0 = fmaf(w1.x, e01.x, a0); a0 = fmaf(w1.y, e01.z, a0);
            a0 = fmaf(w1.z, e23.x, a0); a0 = fmaf(w1.w, e23.z, a0);
            a1 = fmaf(w1.x, e01.y, a1); a1 = fmaf(w1.y, e01.w, a1);
            a1 = fmaf(w1.z, e23.y, a1); a1 = fmaf(w1.w, e23.w, a1);
            ad = fmaf(w2.x, d01.x + d01.y, ad); ad = fmaf(w2.y, d01.z + d01.w, ad);
            ad = fmaf(w2.z, d23.x + d23.y, ad); ad = fmaf(w2.w, d23.z + d23.w, ad);
            cc = fmaf(w1.x, sb.x, cc); cc = fmaf(w1.y, sb.y, cc);
            cc = fmaf(w1.z, sb.z, cc); cc = fmaf(w1.w, sb.w, cc);
            cc = fmaf(w2.x, db.x, cc); cc = fmaf(w2.y, db.y, cc);
            cc = fmaf(w2.z, db.z, cc); cc = fmaf(w2.w, db.w, cc);
            w30 = fmaf(w3.x, e01.x, w30); w30 = fmaf(w3.y, e01.z, w30);
            w30 = fmaf(w3.z, e23.x, w30); w30 = fmaf(w3.w, e23.z, w30);
            w31 = fmaf(w3.x, e01.y, w31); w31 = fmaf(w3.y, e01.w, w31);
            w31 = fmaf(w3.z, e23.y, w31); w31 = fmaf(w3.w, e23.w, w31);
            w3b = fmaf(w3.x, sb.x, w3b); w3b = fmaf(w3.y, sb.y, w3b);
            w3b = fmaf(w3.z, sb.z, w3b); w3b = fmaf(w3.w, sb.w, w3b);
        }
        part[0][q][h] = a0;  part[1][q][h] = a1;  part[2][q][h] = ad;
        part[3][q][h] = cc;  part[4][q][h] = w30; part[5][q][h] = w31;
        part[6][q][h] = w3b;
    }
    __syncthreads();

    // ---- phase 2: reduce partials, build kc ----
    if (t < HH) {
        float r0 = 0.f, r1 = 0.f, r2 = 0.f, r3 = 0.f, r4 = 0.f, r5 = 0.f, r6 = 0.f;
        #pragma unroll
        for (int q = 0; q < 8; ++q) {
            r0 += part[0][q][t]; r1 += part[1][q][t]; r2 += part[2][q][t];
            r3 += part[3][q][t]; r4 += part[4][q][t]; r5 += part[5][q][t];
            r6 += part[6][q][t];
        }
        kc[0][t] = r0 * C1;          // a0*C1
        kc[1][t] = r1 * C1;          // a1*C1
        kc[2][t] = r2 * C1;          // ad*C1
        kc[3][t] = v[t];             // v
        kc[4][t] = r3 * C1;          // cc*C1 (iter-0 bias)
        kc[5][t] = (r3 + r6) * C1;   // (cc+w3b)*C1
        kc[6][t] = r4 * C1;          // w30*C1
        kc[7][t] = r5 * C1;          // w31*C1
    } else if (t < 160) {            // wave 2, lanes 0..31: sum(v)
        int j = t - 128;
        float4 x = ((const float4*)v)[j];
        float s = (x.x + x.y) + (x.z + x.w);
        #pragma unroll
        for (int off = 1; off < 32; off <<= 1) s += __shfl_xor(s, off);
        if (t == 128) svc2_sh = s * C2;
    }
    __syncthreads();

    // ---- phase 3: pin 16 h worth of constants into register pairs ----
    const int h0 = g8 * 16;
    v2f a0_0, a0_1, a0_2, a0_3, a0_4, a0_5, a0_6, a0_7;
    v2f a1_0, a1_1, a1_2, a1_3, a1_4, a1_5, a1_6, a1_7;
    v2f ad_0, ad_1, ad_2, ad_3, ad_4, ad_5, ad_6, ad_7;
    v2f vv_0, vv_1, vv_2, vv_3, vv_4, vv_5, vv_6, vv_7;
    LD16(a0_, 0); LD16(a1_, 1); LD16(ad_, 2); LD16(vv_, 3);
    PIN8(a0_); PIN8(a1_); PIN8(ad_); PIN8(vv_);
    float svc2 = svc2_sh;
    pinf(svc2);
    const v2f one2 = {1.f, 1.f};
    const bool owner = (g8 == 7);

    float X0 = 0.f, X1 = 0.f;

    auto run_iter = [&](int iter, int parity) {
        v2f cg_0, cg_1, cg_2, cg_3, cg_4, cg_5, cg_6, cg_7;
        if (iter == 0) {
            LD16(cg_, 4);
        } else {
            v2f cb_0, cb_1, cb_2, cb_3, cb_4, cb_5, cb_6, cb_7;
            v2f w0_0, w0_1, w0_2, w0_3, w0_4, w0_5, w0_6, w0_7;
            v2f w1_0, w1_1, w1_2, w1_3, w1_4, w1_5, w1_6, w1_7;
            LD16(cb_, 5); LD16(w0_, 6); LD16(w1_, 7);
            v2f X0v = {X0, X0}, X1v = {X1, X1};
            cg_0 = __builtin_elementwise_fma(w0_0, X0v, __builtin_elementwise_fma(w1_0, X1v, cb_0));
            cg_1 = __builtin_elementwise_fma(w0_1, X0v, __builtin_elementwise_fma(w1_1, X1v, cb_1));
            cg_2 = __builtin_elementwise_fma(w0_2, X0v, __builtin_elementwise_fma(w1_2, X1v, cb_2));
            cg_3 = __builtin_elementwise_fma(w0_3, X0v, __builtin_elementwise_fma(w1_3, X1v, cb_3));
            cg_4 = __builtin_elementwise_fma(w0_4, X0v, __builtin_elementwise_fma(w1_4, X1v, cb_4));
            cg_5 = __builtin_elementwise_fma(w0_5, X0v, __builtin_elementwise_fma(w1_5, X1v, cb_5));
            cg_6 = __builtin_elementwise_fma(w0_6, X0v, __builtin_elementwise_fma(w1_6, X1v, cb_6));
            cg_7 = __builtin_elementwise_fma(w0_7, X0v, __builtin_elementwise_fma(w1_7, X1v, cb_7));
        }
        PIN8(cg_);

        float S = 0.f, Sx0 = 0.f, Sx1 = 0.f;
        #pragma unroll
        for (int pass = 0; pass < 8; ++pass) {
            const int s = pass * 128 + sg;
            float4 x = xs[s];
            v2f vx0 = {x.x, x.x}, vx1 = {x.y, x.y}, vyv = {x.z, x.z};
            v2f acc2 = {0.f, 0.f};
            HPAIR(0); HPAIR(1); HPAIR(2); HPAIR(3);
            HPAIR(4); HPAIR(5); HPAIR(6); HPAIR(7);
            float acc = acc2.x + acc2.y;
            // reduce over the 8-lane h-group -> lane g8==7 holds the total
            acc = dpp_add<0x114>(acc);  // row_shr:4
            acc = dpp_add<0x112>(acc);  // row_shr:2
            acc = dpp_add<0x111>(acc);  // row_shr:1
            const bool own = owner && (s < SS);
            float arg = own ? fmaf(-C1, acc, svc2) : -200.f;  // exp2(-200) == +0
            float p = __builtin_amdgcn_exp2f(arg);
            S   += p;
            Sx0  = fmaf(p, x.x, Sx0);
            Sx1  = fmaf(p, x.y, Sx1);
        }
        // wave reduce (non-owner lanes carry exact zeros)
        S   += __shfl_xor(S, 8);   S   += __shfl_xor(S, 16);   S   += __shfl_xor(S, 32);
        Sx0 += __shfl_xor(Sx0, 8); Sx0 += __shfl_xor(Sx0, 16); Sx0 += __shfl_xor(Sx0, 32);
        Sx1 += __shfl_xor(Sx1, 8); Sx1 += __shfl_xor(Sx1, 16); Sx1 += __shfl_xor(Sx1, 32);
        if (lane == 7) red4[parity][wave] = make_float4(S, Sx0, Sx1, 0.f);
        __syncthreads();  // only barrier per iteration
        float4 w4 = red4[parity][lane & 15];
        #pragma unroll
        for (int off = 1; off < 16; off <<= 1) {
            w4.x += __shfl_xor(w4.x, off);
            w4.y += __shfl_xor(w4.y, off);
            w4.z += __shfl_xor(w4.z, off);
        }
        float inv = __builtin_amdgcn_rcpf(w4.x);
        X0 = w4.y * inv;  // uniform across block
        X1 = w4.z * inv;
    };

    run_iter(0, 0);
    run_iter(1, 1);
    run_iter(2, 0);

    // hy[h] = enc_s_w[h,0]*X0 + enc_s_w[h,1]*X1 + enc_s_b[h]
    if (t < HH)
        hy_sh[t] = fmaf(enc_s_w[2 * t], X0, fmaf(enc_s_w[2 * t + 1], X1, enc_s_b[t]));
    __syncthreads();

    // out[b] = lin_w @ relu(dense_w @ hy + dense_b) + lin_b
    float o = 0.f;
    if (t < HH) {
        const float4* dw4 = (const float4*)(dense_w + t * HH);
        const float4* hy4 = (const float4*)hy_sh;
        float r = dense_b[t];
        #pragma unroll 4
        for (int k = 0; k < HH / 4; ++k) {
            float4 d4 = dw4[k], h4 = hy4[k];
            r = fmaf(d4.x, h4.x, fmaf(d4.y, h4.y, fmaf(d4.z, h4.z, fmaf(d4.w, h4.w, r))));
        }
        o = lin_w[t] * fmaxf(r, 0.f);
    }
    #pragma unroll
    for (int off = 32; off > 0; off >>= 1) o += __shfl_xor(o, off);
    if (lane == 0) red4[0][wave].x = o;
    __syncthreads();
    if (t == 0) {
        float s = 0.f;
        for (int i = 0; i < NW; ++i) s += red4[0][i].x;
        out[b] = s + lin_b[0];
    }
}

extern "C" void kernel_launch(void* const* d_in, const int* in_sizes, int n_in,
                              void* d_out, int out_size, void* d_ws, size_t ws_size,
                              hipStream_t stream) {
    const float* stat    = (const float*)d_in[0];
    const float* dyn     = (const float*)d_in[1];
    const float* enc_s_w = (const float*)d_in[2];
    const float* enc_s_b = (const float*)d_in[3];
    const float* enc_d_w = (const float*)d_in[4];
    const float* enc_d_b = (const float*)d_in[5];
    const float* v       = (const float*)d_in[6];
    const float* W       = (const float*)d_in[7];
    const float* dense_w = (const float*)d_in[8];
    const float* dense_b = (const float*)d_in[9];
    const float* lin_w   = (const float*)d_in[10];
    const float* lin_b   = (const float*)d_in[11];
    float* out = (float*)d_out;

    const int B = in_sizes[0] / (2 * SS);

    hipLaunchKernelGGL(sc_fused, dim3(B), dim3(NT), 0, stream,
                       stat, dyn, enc_s_w, enc_s_b, enc_d_w, enc_d_b, v, W,
                       dense_w, dense_b, lin_w, lin_b, out);
}